// Round 4
// baseline (71.160 us; speedup 1.0000x reference)
//
#include <hip/hip_runtime.h>
#include <hip/hip_bf16.h>

#define B_N   32768
#define G_N   2500
#define NB    20
#define GS    50
#define CAP   2048                 // padded slots per bin (real max ~1700, +10 sigma)
#define IC    4                    // i-range split (within block)
#define CSTR  16                   // cnt stride in ints (64B apart)

static __device__ __forceinline__ float fast_exp2(float a) {
#if __has_builtin(__builtin_amdgcn_exp2f)
    return __builtin_amdgcn_exp2f(a);
#else
    return exp2f(a);
#endif
}

// C2 = -2 * log2(e): w = exp(-sq/(2*0.5^2)) = exp(-2*sq) = 2^(C2*sq)
#define C2f (-2.8853900817779268f)

// ---- zero the bin counters (replaces pathological hipMemsetAsync fill) -------
__global__ void zero_cnt(int* __restrict__ cnt) {
    for (int i = threadIdx.x; i < NB * CSTR; i += 64) cnt[i] = 0;
}

// ---- prep: pack P[tb][g] = (m, a0*m, a1*m, 0); counting-sort samples by tb ----
__global__ __launch_bounds__(256) void prep_kernel(
    const float* __restrict__ t, const float* __restrict__ t_edges,
    const float* __restrict__ adj, const int* __restrict__ counts,
    float4* __restrict__ P, int* __restrict__ perm, int* __restrict__ cnt)
{
    int tid = blockIdx.x * 256 + threadIdx.x;
    if (tid < NB * G_N) {
        int c = counts[tid];
        float m = (c > 0) ? 1.0f : 0.0f;
        float a0 = adj[2 * tid], a1 = adj[2 * tid + 1];
        P[tid] = make_float4(m, a0 * m, a1 * m, 0.0f);
    }

    __shared__ int hist[NB];
    __shared__ int lbase[NB];
    if (blockIdx.x < B_N / 256) {          // uniform per block
        if (threadIdx.x < NB) hist[threadIdx.x] = 0;
        __syncthreads();
        float tv = t[tid];
        // searchsorted(t_edges[1:-1], tv, 'left') = #{interior edges < tv} (<=19)
        int tb = 0;
        #pragma unroll
        for (int k = 1; k < NB; ++k) tb += (t_edges[k] < tv) ? 1 : 0;
        int lr = atomicAdd(&hist[tb], 1);              // LDS atomic: cheap
        __syncthreads();
        if (threadIdx.x < NB)
            lbase[threadIdx.x] = atomicAdd(&cnt[threadIdx.x * CSTR], hist[threadIdx.x]);
        __syncthreads();
        int pos = lbase[tb] + lr;
        if (pos < CAP) perm[tb * CAP + pos] = tid;
    }
}

// ---- main: block owns 64 samples x 4 i-chunks; LDS reduce; writes out -------
// grid MUST be NB * (CAP/64) = 640 blocks, bin-major (round-3 bug: 512 blocks
// derived from B_N covered only bins 0..15, leaving bins 16..19 unwritten).
__global__ __launch_bounds__(256) void main_kernel(
    const float* __restrict__ x, const float* __restrict__ gp,
    const float4* __restrict__ P, const int* __restrict__ perm,
    const int* __restrict__ cnt, float* __restrict__ out)
{
    int blk   = blockIdx.x;            // 0..639
    int bin   = blk >> 5;              // 32 blocks per bin (CAP/64), bins 0..19
    int l64   = threadIdx.x & 63;
    int ic    = threadIdx.x >> 6;      // i-chunk 0..3
    int local = (blk & 31) * 64 + l64;

    int nbin = cnt[bin * CSTR];
    if ((blk & 31) * 64 >= nbin) return;   // whole block past the bin's fill
    bool active = local < nbin;

    int sv = perm[bin * CAP + local];      // in-bounds load; value garbage if !active
    int s  = active ? sv : 0;              // select BEFORE use as address

    float x0 = x[2 * s], x1 = x[2 * s + 1];

    // v[j] = exp2(C2*(x1-lin[j])^2), lin[j] = grid_points[j].y  (50 registers)
    float v[GS];
    #pragma unroll
    for (int j = 0; j < GS; ++j) {
        float d = x1 - gp[2 * j + 1];
        v[j] = fast_exp2(C2f * d * d);
    }

    const int i0 = ic * 13;
    const int i1 = (ic == 3) ? GS : (i0 + 13);

    float wsum = 0.0f, a0 = 0.0f, a1 = 0.0f;
    for (int i = i0; i < i1; ++i) {
        float d = x0 - gp[2 * (i * GS)];          // lin[i] = grid_points[i*50].x
        float u = fast_exp2(C2f * d * d);
        const float4* __restrict__ p = P + (bin * G_N + i * GS); // uniform base
        float s0 = 0.0f, s1 = 0.0f, s2 = 0.0f;
        #pragma unroll
        for (int j = 0; j < GS; ++j) {
            float4 q = p[j];                       // wave-uniform 16B load
            s0 = fmaf(v[j], q.x, s0);
            s1 = fmaf(v[j], q.y, s1);
            s2 = fmaf(v[j], q.z, s2);
        }
        wsum = fmaf(u, s0, wsum);
        a0   = fmaf(u, s1, a0);
        a1   = fmaf(u, s2, a1);
    }

    // cross-ic reduction in LDS (3 KB)
    __shared__ float red[3][256];
    red[0][threadIdx.x] = wsum;
    red[1][threadIdx.x] = a0;
    red[2][threadIdx.x] = a1;
    __syncthreads();
    if (ic == 0 && active) {
        float w  = red[0][l64] + red[0][l64 + 64] + red[0][l64 + 128] + red[0][l64 + 192];
        float r0 = red[1][l64] + red[1][l64 + 64] + red[1][l64 + 128] + red[1][l64 + 192];
        float r1 = red[2][l64] + red[2][l64 + 64] + red[2][l64 + 128] + red[2][l64 + 192];
        w += 1e-10f;
        out[2 * s]     = -r0 / w;
        out[2 * s + 1] = -r1 / w;
    }
}

// ---- fallback (no workspace): direct separable compute ------------------------
__global__ __launch_bounds__(256) void fallback_kernel(
    const float* __restrict__ t, const float* __restrict__ x,
    const float* __restrict__ gp, const float* __restrict__ adj,
    const float* __restrict__ t_edges, const int* __restrict__ counts,
    float* __restrict__ out)
{
    int s = blockIdx.x * 256 + threadIdx.x;
    if (s >= B_N) return;
    float tv = t[s];
    int tb = 0;
    #pragma unroll
    for (int k = 1; k < NB; ++k) tb += (t_edges[k] < tv) ? 1 : 0;
    if (tb > NB - 1) tb = NB - 1;
    float x0 = x[2 * s], x1 = x[2 * s + 1];
    float v[GS];
    #pragma unroll
    for (int j = 0; j < GS; ++j) {
        float d = x1 - gp[2 * j + 1];
        v[j] = fast_exp2(C2f * d * d);
    }
    float wsum = 0.0f, a0 = 0.0f, a1 = 0.0f;
    for (int i = 0; i < GS; ++i) {
        float d = x0 - gp[2 * (i * GS)];
        float u = fast_exp2(C2f * d * d);
        int gbase = tb * G_N + i * GS;
        float s0 = 0.0f, s1 = 0.0f, s2 = 0.0f;
        #pragma unroll
        for (int j = 0; j < GS; ++j) {
            int g = gbase + j;
            float m = (counts[g] > 0) ? 1.0f : 0.0f;
            float vm = v[j] * m;
            s0 += vm;
            s1 = fmaf(vm, adj[2 * g], s1);
            s2 = fmaf(vm, adj[2 * g + 1], s2);
        }
        wsum = fmaf(u, s0, wsum);
        a0   = fmaf(u, s1, a0);
        a1   = fmaf(u, s2, a1);
    }
    wsum += 1e-10f;
    out[2 * s]     = -a0 / wsum;
    out[2 * s + 1] = -a1 / wsum;
}

extern "C" void kernel_launch(void* const* d_in, const int* in_sizes, int n_in,
                              void* d_out, int out_size, void* d_ws, size_t ws_size,
                              hipStream_t stream)
{
    const float* t      = (const float*)d_in[0];   // (B,1)
    const float* x      = (const float*)d_in[1];   // (B,2)
    const float* gp     = (const float*)d_in[2];   // (G,2)
    const float* adj    = (const float*)d_in[3];   // (NB,G,2)
    const float* te     = (const float*)d_in[4];   // (NB+1,)
    const int*   counts = (const int*)d_in[5];     // (NB,G)
    float*       out    = (float*)d_out;

    const size_t OFF_P    = 0;
    const size_t SZ_P     = (size_t)NB * G_N * 16;            // 800000
    const size_t OFF_PERM = OFF_P + SZ_P;
    const size_t SZ_PERM  = (size_t)NB * CAP * 4;             // 163840
    const size_t OFF_CNT  = OFF_PERM + SZ_PERM;
    const size_t SZ_CNT   = (size_t)NB * CSTR * 4;            // 1280
    const size_t NEED     = OFF_CNT + SZ_CNT;

    if (ws_size < NEED) {
        fallback_kernel<<<(B_N + 255) / 256, 256, 0, stream>>>(
            t, x, gp, adj, te, counts, out);
        return;
    }

    char* ws = (char*)d_ws;
    float4* P    = (float4*)(ws + OFF_P);
    int*    perm = (int*)(ws + OFF_PERM);
    int*    cnt  = (int*)(ws + OFF_CNT);

    zero_cnt<<<1, 64, 0, stream>>>(cnt);
    prep_kernel<<<(NB * G_N + 255) / 256, 256, 0, stream>>>(
        t, te, adj, counts, P, perm, cnt);
    main_kernel<<<NB * (CAP / 64), 256, 0, stream>>>(x, gp, P, perm, cnt, out);
}

// Round 5
// 66.193 us; speedup vs baseline: 1.0750x; 1.0750x over previous
//
#include <hip/hip_runtime.h>
#include <hip/hip_bf16.h>

#define B_N   32768
#define G_N   2500
#define NB    20
#define GS    50
#define CAP   2048                 // padded slots per bin (real max ~1700, +10 sigma)
#define IC    4                    // i-range split (within block)
#define CSTR  16                   // cnt stride in ints (64B apart)

static __device__ __forceinline__ float fast_exp2(float a) {
#if __has_builtin(__builtin_amdgcn_exp2f)
    return __builtin_amdgcn_exp2f(a);
#else
    return exp2f(a);
#endif
}

// C2 = -2 * log2(e): w = exp(-sq/(2*0.5^2)) = exp(-2*sq) = 2^(C2*sq)
#define C2f (-2.8853900817779268f)

// ---- zero the bin counters (replaces pathological hipMemsetAsync fill) -------
__global__ void zero_cnt(int* __restrict__ cnt) {
    for (int i = threadIdx.x; i < NB * CSTR; i += 64) cnt[i] = 0;
}

// ---- prep: pack P[tb][g] = (m, a0*m, a1*m, 0); counting-sort samples by tb ----
__global__ __launch_bounds__(256) void prep_kernel(
    const float* __restrict__ t, const float* __restrict__ t_edges,
    const float* __restrict__ adj, const int* __restrict__ counts,
    float4* __restrict__ P, int* __restrict__ perm, int* __restrict__ cnt)
{
    int tid = blockIdx.x * 256 + threadIdx.x;
    if (tid < NB * G_N) {
        int c = counts[tid];
        float m = (c > 0) ? 1.0f : 0.0f;
        float a0 = adj[2 * tid], a1 = adj[2 * tid + 1];
        P[tid] = make_float4(m, a0 * m, a1 * m, 0.0f);
    }

    __shared__ int hist[NB];
    __shared__ int lbase[NB];
    if (blockIdx.x < B_N / 256) {          // uniform per block
        if (threadIdx.x < NB) hist[threadIdx.x] = 0;
        __syncthreads();
        float tv = t[tid];
        // searchsorted(t_edges[1:-1], tv, 'left') = #{interior edges < tv} (<=19)
        int tb = 0;
        #pragma unroll
        for (int k = 1; k < NB; ++k) tb += (t_edges[k] < tv) ? 1 : 0;
        int lr = atomicAdd(&hist[tb], 1);              // LDS atomic: cheap
        __syncthreads();
        if (threadIdx.x < NB)
            lbase[threadIdx.x] = atomicAdd(&cnt[threadIdx.x * CSTR], hist[threadIdx.x]);
        __syncthreads();
        int pos = lbase[tb] + lr;
        if (pos < CAP) perm[tb * CAP + pos] = tid;
    }
}

// ---- main: block owns 64 samples x 4 i-chunks; LDS reduce; writes out -------
// grid = NB * (CAP/64) = 640 blocks, bin-major.
// ic MUST be an SGPR (readfirstlane): round-4 regression was ic=tid>>6 making
// the P row pointer per-lane (VGPR) -> gather loads, latency-bound 67us.
__global__ __launch_bounds__(256) void main_kernel(
    const float* __restrict__ x, const float* __restrict__ gp,
    const float4* __restrict__ P, const int* __restrict__ perm,
    const int* __restrict__ cnt, float* __restrict__ out)
{
    int blk   = blockIdx.x;            // 0..639
    int bin   = blk >> 5;              // 32 blocks per bin (CAP/64), bins 0..19
    int l64   = threadIdx.x & 63;
    // wave-uniform by construction (wave w = threads 64w..64w+63); readfirstlane
    // lands it in an SGPR so the compiler can prove scalar addressing below.
    int ic    = __builtin_amdgcn_readfirstlane(threadIdx.x >> 6);   // 0..3
    int local = (blk & 31) * 64 + l64;

    int nbin = cnt[bin * CSTR];
    if ((blk & 31) * 64 >= nbin) return;   // whole block past the bin's fill
    bool active = local < nbin;

    int sv = perm[bin * CAP + local];      // in-bounds load; value garbage if !active
    int s  = active ? sv : 0;              // select BEFORE use as address

    float x0 = x[2 * s], x1 = x[2 * s + 1];

    // v[j] = exp2(C2*(x1-lin[j])^2), lin[j] = grid_points[j].y  (50 registers)
    float v[GS];
    #pragma unroll
    for (int j = 0; j < GS; ++j) {
        float d = x1 - gp[2 * j + 1];
        v[j] = fast_exp2(C2f * d * d);
    }

    const int i0 = ic * 13;
    const int i1 = (ic == 3) ? GS : (i0 + 13);

    float wsum = 0.0f, a0 = 0.0f, a1 = 0.0f;
    for (int i = i0; i < i1; ++i) {
        float d = x0 - gp[2 * (i * GS)];          // lin[i] = grid_points[i*50].x
        float u = fast_exp2(C2f * d * d);
        const float4* __restrict__ p = P + (bin * G_N + i * GS); // scalar base
        float s0 = 0.0f, s1 = 0.0f, s2 = 0.0f;
        #pragma unroll
        for (int j = 0; j < GS; ++j) {
            float4 q = p[j];                       // wave-uniform 16B load
            s0 = fmaf(v[j], q.x, s0);
            s1 = fmaf(v[j], q.y, s1);
            s2 = fmaf(v[j], q.z, s2);
        }
        wsum = fmaf(u, s0, wsum);
        a0   = fmaf(u, s1, a0);
        a1   = fmaf(u, s2, a1);
    }

    // cross-ic reduction in LDS (3 KB)
    __shared__ float red[3][256];
    red[0][threadIdx.x] = wsum;
    red[1][threadIdx.x] = a0;
    red[2][threadIdx.x] = a1;
    __syncthreads();
    if (ic == 0 && active) {
        float w  = red[0][l64] + red[0][l64 + 64] + red[0][l64 + 128] + red[0][l64 + 192];
        float r0 = red[1][l64] + red[1][l64 + 64] + red[1][l64 + 128] + red[1][l64 + 192];
        float r1 = red[2][l64] + red[2][l64 + 64] + red[2][l64 + 128] + red[2][l64 + 192];
        w += 1e-10f;
        out[2 * s]     = -r0 / w;
        out[2 * s + 1] = -r1 / w;
    }
}

// ---- fallback (no workspace): direct separable compute ------------------------
__global__ __launch_bounds__(256) void fallback_kernel(
    const float* __restrict__ t, const float* __restrict__ x,
    const float* __restrict__ gp, const float* __restrict__ adj,
    const float* __restrict__ t_edges, const int* __restrict__ counts,
    float* __restrict__ out)
{
    int s = blockIdx.x * 256 + threadIdx.x;
    if (s >= B_N) return;
    float tv = t[s];
    int tb = 0;
    #pragma unroll
    for (int k = 1; k < NB; ++k) tb += (t_edges[k] < tv) ? 1 : 0;
    if (tb > NB - 1) tb = NB - 1;
    float x0 = x[2 * s], x1 = x[2 * s + 1];
    float v[GS];
    #pragma unroll
    for (int j = 0; j < GS; ++j) {
        float d = x1 - gp[2 * j + 1];
        v[j] = fast_exp2(C2f * d * d);
    }
    float wsum = 0.0f, a0 = 0.0f, a1 = 0.0f;
    for (int i = 0; i < GS; ++i) {
        float d = x0 - gp[2 * (i * GS)];
        float u = fast_exp2(C2f * d * d);
        int gbase = tb * G_N + i * GS;
        float s0 = 0.0f, s1 = 0.0f, s2 = 0.0f;
        #pragma unroll
        for (int j = 0; j < GS; ++j) {
            int g = gbase + j;
            float m = (counts[g] > 0) ? 1.0f : 0.0f;
            float vm = v[j] * m;
            s0 += vm;
            s1 = fmaf(vm, adj[2 * g], s1);
            s2 = fmaf(vm, adj[2 * g + 1], s2);
        }
        wsum = fmaf(u, s0, wsum);
        a0   = fmaf(u, s1, a0);
        a1   = fmaf(u, s2, a1);
    }
    wsum += 1e-10f;
    out[2 * s]     = -a0 / wsum;
    out[2 * s + 1] = -a1 / wsum;
}

extern "C" void kernel_launch(void* const* d_in, const int* in_sizes, int n_in,
                              void* d_out, int out_size, void* d_ws, size_t ws_size,
                              hipStream_t stream)
{
    const float* t      = (const float*)d_in[0];   // (B,1)
    const float* x      = (const float*)d_in[1];   // (B,2)
    const float* gp     = (const float*)d_in[2];   // (G,2)
    const float* adj    = (const float*)d_in[3];   // (NB,G,2)
    const float* te     = (const float*)d_in[4];   // (NB+1,)
    const int*   counts = (const int*)d_in[5];     // (NB,G)
    float*       out    = (float*)d_out;

    const size_t OFF_P    = 0;
    const size_t SZ_P     = (size_t)NB * G_N * 16;            // 800000
    const size_t OFF_PERM = OFF_P + SZ_P;
    const size_t SZ_PERM  = (size_t)NB * CAP * 4;             // 163840
    const size_t OFF_CNT  = OFF_PERM + SZ_PERM;
    const size_t SZ_CNT   = (size_t)NB * CSTR * 4;            // 1280
    const size_t NEED     = OFF_CNT + SZ_CNT;

    if (ws_size < NEED) {
        fallback_kernel<<<(B_N + 255) / 256, 256, 0, stream>>>(
            t, x, gp, adj, te, counts, out);
        return;
    }

    char* ws = (char*)d_ws;
    float4* P    = (float4*)(ws + OFF_P);
    int*    perm = (int*)(ws + OFF_PERM);
    int*    cnt  = (int*)(ws + OFF_CNT);

    zero_cnt<<<1, 64, 0, stream>>>(cnt);
    prep_kernel<<<(NB * G_N + 255) / 256, 256, 0, stream>>>(
        t, te, adj, counts, P, perm, cnt);
    main_kernel<<<NB * (CAP / 64), 256, 0, stream>>>(x, gp, P, perm, cnt, out);
}

// Round 6
// 49.358 us; speedup vs baseline: 1.4417x; 1.3411x over previous
//
#include <hip/hip_runtime.h>
#include <hip/hip_bf16.h>

#define B_N   32768
#define G_N   2500
#define NB    20
#define GS    50
#define CAP   2048                 // padded slots per bin (max real ~1700, 10 sigma)
#define CPB   (CAP/256)            // chunks per bin = 8
#define IC    4                    // i-range split for parallelism
#define CSTR  16                   // cnt stride in ints (64B apart -> no same-line atomics)

static __device__ __forceinline__ float fast_exp2(float a) {
#if __has_builtin(__builtin_amdgcn_exp2f)
    return __builtin_amdgcn_exp2f(a);
#else
    return exp2f(a);
#endif
}

// C2 = -2 * log2(e): w = exp(-sq/(2*0.5^2)) = exp(-2*sq) = 2^(C2*sq)
#define C2f (-2.8853900817779268f)

// ---- zero the bin counters (replaces the 39us pathological tiny memset) ------
__global__ void zero_cnt(int* __restrict__ cnt) {
    for (int i = threadIdx.x; i < NB * CSTR; i += 64) cnt[i] = 0;
}

// ---- prep: pack P[tb][g] = (m, a0*m, a1*m, 0); counting-sort samples by tb ----
__global__ __launch_bounds__(256) void prep_kernel(
    const float* __restrict__ t, const float* __restrict__ t_edges,
    const float* __restrict__ adj, const int* __restrict__ counts,
    float4* __restrict__ P, int* __restrict__ perm, int* __restrict__ cnt)
{
    int tid = blockIdx.x * 256 + threadIdx.x;
    if (tid < NB * G_N) {
        int c = counts[tid];
        float m = (c > 0) ? 1.0f : 0.0f;
        float a0 = adj[2 * tid], a1 = adj[2 * tid + 1];
        P[tid] = make_float4(m, a0 * m, a1 * m, 0.0f);
    }

    __shared__ int hist[NB];
    __shared__ int lbase[NB];
    if (blockIdx.x < B_N / 256) {          // uniform per block
        if (threadIdx.x < NB) hist[threadIdx.x] = 0;
        __syncthreads();
        float tv = t[tid];
        // searchsorted(t_edges[1:-1], tv, 'left') = #{interior edges < tv} (<=19)
        int tb = 0;
        #pragma unroll
        for (int k = 1; k < NB; ++k) tb += (t_edges[k] < tv) ? 1 : 0;
        int lr = atomicAdd(&hist[tb], 1);              // LDS atomic: cheap
        __syncthreads();
        if (threadIdx.x < NB)
            lbase[threadIdx.x] = atomicAdd(&cnt[threadIdx.x * CSTR], hist[threadIdx.x]);
        __syncthreads();
        int pos = lbase[tb] + lr;
        if (pos < CAP) perm[tb * CAP + pos] = tid;
    }
}

// ---- main: separable weighted sums, partials per i-chunk (round-2 proven) ----
__global__ __launch_bounds__(256) void main_kernel(
    const float* __restrict__ x, const float* __restrict__ gp,
    const float4* __restrict__ P, const int* __restrict__ perm,
    const int* __restrict__ cnt, float4* __restrict__ partials)
{
    int bid   = blockIdx.x;
    int ic    = bid & 3;           // i-chunk (SGPR: from blockIdx)
    int bc    = bid >> 2;          // 0..159
    int bin   = bc >> 3;           // time bin (uniform per block -> SGPR)
    int chunk = bc & 7;
    int local = chunk * 256 + threadIdx.x;

    int nbin = cnt[bin * CSTR];
    if (chunk * 256 >= nbin) return;       // whole block past the bin's fill
    bool active = local < nbin;

    int s  = perm[bin * CAP + local];      // in-bounds load; garbage if !active
    int ss = active ? s : 0;

    float x0 = x[2 * ss], x1 = x[2 * ss + 1];

    // v[j] = exp2(C2*(x1-lin[j])^2), lin[j] = grid_points[j].y  (50 registers)
    float v[GS];
    #pragma unroll
    for (int j = 0; j < GS; ++j) {
        float d = x1 - gp[2 * j + 1];
        v[j] = fast_exp2(C2f * d * d);
    }

    const int i0 = ic * 13;
    const int i1 = (ic == 3) ? GS : (i0 + 13);

    float wsum = 0.0f, a0 = 0.0f, a1 = 0.0f;
    for (int i = i0; i < i1; ++i) {
        float d = x0 - gp[2 * (i * GS)];          // lin[i] = grid_points[i*50].x
        float u = fast_exp2(C2f * d * d);
        const float4* __restrict__ p = P + (bin * G_N + i * GS); // uniform base
        float s0 = 0.0f, s1 = 0.0f, s2 = 0.0f;
        #pragma unroll
        for (int j = 0; j < GS; ++j) {
            float4 q = p[j];                       // wave-uniform 16B load
            s0 = fmaf(v[j], q.x, s0);
            s1 = fmaf(v[j], q.y, s1);
            s2 = fmaf(v[j], q.z, s2);
        }
        wsum = fmaf(u, s0, wsum);
        a0   = fmaf(u, s1, a0);
        a1   = fmaf(u, s2, a1);
    }
    if (active)
        partials[ic * (NB * CAP) + bin * CAP + local] = make_float4(wsum, a0, a1, 0.0f);
}

// ---- finalize: sum i-chunk partials, divide, negate ---------------------------
__global__ __launch_bounds__(256) void fin_kernel(
    const int* __restrict__ perm, const int* __restrict__ cnt,
    const float4* __restrict__ partials, float* __restrict__ out)
{
    int slot  = blockIdx.x * 256 + threadIdx.x;    // 0..NB*CAP-1
    int bin   = slot >> 11;                        // CAP = 2048
    int local = slot & (CAP - 1);
    if (local >= cnt[bin * CSTR]) return;
    int s = perm[slot];
    float w = 0.0f, a0 = 0.0f, a1 = 0.0f;
    #pragma unroll
    for (int ic = 0; ic < IC; ++ic) {
        float4 q = partials[ic * (NB * CAP) + slot];
        w += q.x; a0 += q.y; a1 += q.z;
    }
    w += 1e-10f;
    out[2 * s]     = -a0 / w;
    out[2 * s + 1] = -a1 / w;
}

// ---- fallback (no workspace): direct separable compute ------------------------
__global__ __launch_bounds__(256) void fallback_kernel(
    const float* __restrict__ t, const float* __restrict__ x,
    const float* __restrict__ gp, const float* __restrict__ adj,
    const float* __restrict__ t_edges, const int* __restrict__ counts,
    float* __restrict__ out)
{
    int s = blockIdx.x * 256 + threadIdx.x;
    if (s >= B_N) return;
    float tv = t[s];
    int tb = 0;
    #pragma unroll
    for (int k = 1; k < NB; ++k) tb += (t_edges[k] < tv) ? 1 : 0;
    if (tb > NB - 1) tb = NB - 1;
    float x0 = x[2 * s], x1 = x[2 * s + 1];
    float v[GS];
    #pragma unroll
    for (int j = 0; j < GS; ++j) {
        float d = x1 - gp[2 * j + 1];
        v[j] = fast_exp2(C2f * d * d);
    }
    float wsum = 0.0f, a0 = 0.0f, a1 = 0.0f;
    for (int i = 0; i < GS; ++i) {
        float d = x0 - gp[2 * (i * GS)];
        float u = fast_exp2(C2f * d * d);
        int gbase = tb * G_N + i * GS;
        float s0 = 0.0f, s1 = 0.0f, s2 = 0.0f;
        #pragma unroll
        for (int j = 0; j < GS; ++j) {
            int g = gbase + j;
            float m = (counts[g] > 0) ? 1.0f : 0.0f;
            float vm = v[j] * m;
            s0 += vm;
            s1 = fmaf(vm, adj[2 * g], s1);
            s2 = fmaf(vm, adj[2 * g + 1], s2);
        }
        wsum = fmaf(u, s0, wsum);
        a0   = fmaf(u, s1, a0);
        a1   = fmaf(u, s2, a1);
    }
    wsum += 1e-10f;
    out[2 * s]     = -a0 / wsum;
    out[2 * s + 1] = -a1 / wsum;
}

extern "C" void kernel_launch(void* const* d_in, const int* in_sizes, int n_in,
                              void* d_out, int out_size, void* d_ws, size_t ws_size,
                              hipStream_t stream)
{
    const float* t      = (const float*)d_in[0];   // (B,1)
    const float* x      = (const float*)d_in[1];   // (B,2)
    const float* gp     = (const float*)d_in[2];   // (G,2)
    const float* adj    = (const float*)d_in[3];   // (NB,G,2)
    const float* te     = (const float*)d_in[4];   // (NB+1,)
    const int*   counts = (const int*)d_in[5];     // (NB,G)
    float*       out    = (float*)d_out;

    const size_t OFF_P    = 0;
    const size_t SZ_P     = (size_t)NB * G_N * 16;            // 800000
    const size_t OFF_PART = OFF_P + SZ_P;
    const size_t SZ_PART  = (size_t)IC * NB * CAP * 16;       // 2621440
    const size_t OFF_PERM = OFF_PART + SZ_PART;
    const size_t SZ_PERM  = (size_t)NB * CAP * 4;             // 163840
    const size_t OFF_CNT  = OFF_PERM + SZ_PERM;
    const size_t SZ_CNT   = (size_t)NB * CSTR * 4;            // 1280
    const size_t NEED     = OFF_CNT + SZ_CNT;

    if (ws_size < NEED) {
        fallback_kernel<<<(B_N + 255) / 256, 256, 0, stream>>>(
            t, x, gp, adj, te, counts, out);
        return;
    }

    char* ws = (char*)d_ws;
    float4* P        = (float4*)(ws + OFF_P);
    float4* partials = (float4*)(ws + OFF_PART);
    int*    perm     = (int*)(ws + OFF_PERM);
    int*    cnt      = (int*)(ws + OFF_CNT);

    zero_cnt<<<1, 64, 0, stream>>>(cnt);
    prep_kernel<<<(NB * G_N + 255) / 256, 256, 0, stream>>>(
        t, te, adj, counts, P, perm, cnt);
    main_kernel<<<NB * CPB * IC, 256, 0, stream>>>(x, gp, P, perm, cnt, partials);
    fin_kernel<<<NB * CAP / 256, 256, 0, stream>>>(perm, cnt, partials, out);
}

// Round 7
// 48.455 us; speedup vs baseline: 1.4686x; 1.0186x over previous
//
#include <hip/hip_runtime.h>
#include <hip/hip_bf16.h>

#define B_N   32768
#define G_N   2500
#define NB    20
#define GS    50
#define CAP   2048                 // padded slots per bin (max real ~1700, 10 sigma)
#define CPB   (CAP/256)            // chunks per bin = 8
#define IC    4                    // i-range split for parallelism
#define CSTR  16                   // cnt stride in ints (64B apart -> no same-line atomics)

static __device__ __forceinline__ float fast_exp2(float a) {
#if __has_builtin(__builtin_amdgcn_exp2f)
    return __builtin_amdgcn_exp2f(a);
#else
    return exp2f(a);
#endif
}

// C2 = -2 * log2(e): w = exp(-sq/(2*0.5^2)) = exp(-2*sq) = 2^(C2*sq)
#define C2f (-2.8853900817779268f)

// ---- zero the bin counters ---------------------------------------------------
__global__ void zero_cnt(int* __restrict__ cnt) {
    for (int i = threadIdx.x; i < NB * CSTR; i += 64) cnt[i] = 0;
}

// ---- prep: pack P[tb][g] = (m, a0*m, a1*m, 0); counting-sort samples by tb ----
__global__ __launch_bounds__(256) void prep_kernel(
    const float* __restrict__ t, const float* __restrict__ t_edges,
    const float* __restrict__ adj, const int* __restrict__ counts,
    float4* __restrict__ P, int* __restrict__ perm, int* __restrict__ cnt)
{
    int tid = blockIdx.x * 256 + threadIdx.x;
    if (tid < NB * G_N) {
        int c = counts[tid];
        float m = (c > 0) ? 1.0f : 0.0f;
        float a0 = adj[2 * tid], a1 = adj[2 * tid + 1];
        P[tid] = make_float4(m, a0 * m, a1 * m, 0.0f);
    }

    __shared__ int hist[NB];
    __shared__ int lbase[NB];
    if (blockIdx.x < B_N / 256) {          // uniform per block
        if (threadIdx.x < NB) hist[threadIdx.x] = 0;
        __syncthreads();
        float tv = t[tid];
        // searchsorted(t_edges[1:-1], tv, 'left') = #{interior edges < tv} (<=19)
        int tb = 0;
        #pragma unroll
        for (int k = 1; k < NB; ++k) tb += (t_edges[k] < tv) ? 1 : 0;
        int lr = atomicAdd(&hist[tb], 1);              // LDS atomic: cheap
        __syncthreads();
        if (threadIdx.x < NB)
            lbase[threadIdx.x] = atomicAdd(&cnt[threadIdx.x * CSTR], hist[threadIdx.x]);
        __syncthreads();
        int pos = lbase[tb] + lr;
        if (pos < CAP) perm[tb * CAP + pos] = tid;
    }
}

// ---- main: LDS-staged P slice; separable weighted sums; partials per i-chunk --
// Round-6 diagnosis: 650 wave-uniform global float4 loads/thread are latency-
// bound (~36us, VALUBusy 9%). Fix: coop-stage the contiguous 10.4KB slice into
// LDS once per block; j-loop reads are same-address broadcasts (conflict-free).
__global__ __launch_bounds__(256) void main_kernel(
    const float* __restrict__ x, const float* __restrict__ gp,
    const float4* __restrict__ P, const int* __restrict__ perm,
    const int* __restrict__ cnt, float4* __restrict__ partials)
{
    int bid   = blockIdx.x;
    int ic    = bid & 3;           // i-chunk (SGPR: from blockIdx)
    int bc    = bid >> 2;          // 0..159
    int bin   = bc >> 3;           // time bin (SGPR)
    int chunk = bc & 7;
    int local = chunk * 256 + threadIdx.x;

    int nbin = cnt[bin * CSTR];
    if (chunk * 256 >= nbin) return;       // block-uniform early exit (before staging)
    bool active = local < nbin;

    const int i0    = ic * 13;
    const int i1    = (ic == 3) ? GS : (i0 + 13);
    const int nelem = (i1 - i0) * GS;      // 650 or 550

    // cooperative stage: rows i0..i1-1 are CONTIGUOUS in P -> linear coalesced copy
    __shared__ float4 tile[13 * GS];       // 10.4 KB
    {
        const float4* __restrict__ src = P + (bin * G_N + i0 * GS);
        for (int e = threadIdx.x; e < nelem; e += 256)
            tile[e] = src[e];
    }

    int s  = perm[bin * CAP + local];      // in-bounds load; garbage if !active
    int ss = active ? s : 0;
    float x0 = x[2 * ss], x1 = x[2 * ss + 1];

    // v[j] = exp2(C2*(x1-lin[j])^2), lin[j] = grid_points[j].y  (50 registers)
    float v[GS];
    #pragma unroll
    for (int j = 0; j < GS; ++j) {
        float d = x1 - gp[2 * j + 1];
        v[j] = fast_exp2(C2f * d * d);
    }

    __syncthreads();                       // staging complete

    float wsum = 0.0f, a0 = 0.0f, a1 = 0.0f;
    for (int i = i0; i < i1; ++i) {
        float d = x0 - gp[2 * (i * GS)];          // lin[i] = grid_points[i*50].x
        float u = fast_exp2(C2f * d * d);
        const float4* p = &tile[(i - i0) * GS];
        float s0 = 0.0f, s1 = 0.0f, s2 = 0.0f;
        #pragma unroll
        for (int j = 0; j < GS; ++j) {
            float4 q = p[j];                       // LDS broadcast (same addr all lanes)
            s0 = fmaf(v[j], q.x, s0);
            s1 = fmaf(v[j], q.y, s1);
            s2 = fmaf(v[j], q.z, s2);
        }
        wsum = fmaf(u, s0, wsum);
        a0   = fmaf(u, s1, a0);
        a1   = fmaf(u, s2, a1);
    }
    if (active)
        partials[ic * (NB * CAP) + bin * CAP + local] = make_float4(wsum, a0, a1, 0.0f);
}

// ---- finalize: sum i-chunk partials, divide, negate ---------------------------
__global__ __launch_bounds__(256) void fin_kernel(
    const int* __restrict__ perm, const int* __restrict__ cnt,
    const float4* __restrict__ partials, float* __restrict__ out)
{
    int slot  = blockIdx.x * 256 + threadIdx.x;    // 0..NB*CAP-1
    int bin   = slot >> 11;                        // CAP = 2048
    int local = slot & (CAP - 1);
    if (local >= cnt[bin * CSTR]) return;
    int s = perm[slot];
    float w = 0.0f, a0 = 0.0f, a1 = 0.0f;
    #pragma unroll
    for (int ic = 0; ic < IC; ++ic) {
        float4 q = partials[ic * (NB * CAP) + slot];
        w += q.x; a0 += q.y; a1 += q.z;
    }
    w += 1e-10f;
    out[2 * s]     = -a0 / w;
    out[2 * s + 1] = -a1 / w;
}

// ---- fallback (no workspace): direct separable compute ------------------------
__global__ __launch_bounds__(256) void fallback_kernel(
    const float* __restrict__ t, const float* __restrict__ x,
    const float* __restrict__ gp, const float* __restrict__ adj,
    const float* __restrict__ t_edges, const int* __restrict__ counts,
    float* __restrict__ out)
{
    int s = blockIdx.x * 256 + threadIdx.x;
    if (s >= B_N) return;
    float tv = t[s];
    int tb = 0;
    #pragma unroll
    for (int k = 1; k < NB; ++k) tb += (t_edges[k] < tv) ? 1 : 0;
    if (tb > NB - 1) tb = NB - 1;
    float x0 = x[2 * s], x1 = x[2 * s + 1];
    float v[GS];
    #pragma unroll
    for (int j = 0; j < GS; ++j) {
        float d = x1 - gp[2 * j + 1];
        v[j] = fast_exp2(C2f * d * d);
    }
    float wsum = 0.0f, a0 = 0.0f, a1 = 0.0f;
    for (int i = 0; i < GS; ++i) {
        float d = x0 - gp[2 * (i * GS)];
        float u = fast_exp2(C2f * d * d);
        int gbase = tb * G_N + i * GS;
        float s0 = 0.0f, s1 = 0.0f, s2 = 0.0f;
        #pragma unroll
        for (int j = 0; j < GS; ++j) {
            int g = gbase + j;
            float m = (counts[g] > 0) ? 1.0f : 0.0f;
            float vm = v[j] * m;
            s0 += vm;
            s1 = fmaf(vm, adj[2 * g], s1);
            s2 = fmaf(vm, adj[2 * g + 1], s2);
        }
        wsum = fmaf(u, s0, wsum);
        a0   = fmaf(u, s1, a0);
        a1   = fmaf(u, s2, a1);
    }
    wsum += 1e-10f;
    out[2 * s]     = -a0 / wsum;
    out[2 * s + 1] = -a1 / wsum;
}

extern "C" void kernel_launch(void* const* d_in, const int* in_sizes, int n_in,
                              void* d_out, int out_size, void* d_ws, size_t ws_size,
                              hipStream_t stream)
{
    const float* t      = (const float*)d_in[0];   // (B,1)
    const float* x      = (const float*)d_in[1];   // (B,2)
    const float* gp     = (const float*)d_in[2];   // (G,2)
    const float* adj    = (const float*)d_in[3];   // (NB,G,2)
    const float* te     = (const float*)d_in[4];   // (NB+1,)
    const int*   counts = (const int*)d_in[5];     // (NB,G)
    float*       out    = (float*)d_out;

    const size_t OFF_P    = 0;
    const size_t SZ_P     = (size_t)NB * G_N * 16;            // 800000
    const size_t OFF_PART = OFF_P + SZ_P;
    const size_t SZ_PART  = (size_t)IC * NB * CAP * 16;       // 2621440
    const size_t OFF_PERM = OFF_PART + SZ_PART;
    const size_t SZ_PERM  = (size_t)NB * CAP * 4;             // 163840
    const size_t OFF_CNT  = OFF_PERM + SZ_PERM;
    const size_t SZ_CNT   = (size_t)NB * CSTR * 4;            // 1280
    const size_t NEED     = OFF_CNT + SZ_CNT;

    if (ws_size < NEED) {
        fallback_kernel<<<(B_N + 255) / 256, 256, 0, stream>>>(
            t, x, gp, adj, te, counts, out);
        return;
    }

    char* ws = (char*)d_ws;
    float4* P        = (float4*)(ws + OFF_P);
    float4* partials = (float4*)(ws + OFF_PART);
    int*    perm     = (int*)(ws + OFF_PERM);
    int*    cnt      = (int*)(ws + OFF_CNT);

    zero_cnt<<<1, 64, 0, stream>>>(cnt);
    prep_kernel<<<(NB * G_N + 255) / 256, 256, 0, stream>>>(
        t, te, adj, counts, P, perm, cnt);
    main_kernel<<<NB * CPB * IC, 256, 0, stream>>>(x, gp, P, perm, cnt, partials);
    fin_kernel<<<NB * CAP / 256, 256, 0, stream>>>(perm, cnt, partials, out);
}